// Round 1
// 849.619 us; speedup vs baseline: 1.1270x; 1.1270x over previous
//
#include <hip/hip_runtime.h>
#include <stdint.h>

#define M_DIM 2048
#define N_DIM 4096
#define K_DIM 11008
#define NN    11008
#define KTOK  2201    // int(11008*0.2)
#define NSEL  4403    // int(11008*0.4)
#define NCHUNK 43     // 43*256 == 11008
#define NBINS 2049    // counts in [0,2048]
#define NWORDS 344    // 11008/32 mask words per row
#define NC64  172     // 11008/64 ballot chunks per row

typedef __bf16 bf16x8_t __attribute__((ext_vector_type(8)));
typedef float  f32x4_t  __attribute__((ext_vector_type(4)));

__device__ __forceinline__ unsigned short f2bf(float f) {
  unsigned u = __float_as_uint(f);
  u = (u + 0x7FFFu + ((u >> 16) & 1u)) >> 16;   // round-to-nearest-even
  return (unsigned short)u;
}

__device__ __forceinline__ unsigned fkey(unsigned v) {
  return v ^ ((unsigned)((int)v >> 31) | 0x80000000u);
}

// ---------------- f32 -> bf16 conversion (vectorized) ----------------
__global__ __launch_bounds__(256) void cvt_f32_bf16(const float4* __restrict__ src,
                                                    ushort4* __restrict__ dst, int n4) {
  int i = blockIdx.x * 256 + threadIdx.x;
  int stride = gridDim.x * 256;
  for (; i < n4; i += stride) {
    float4 v = src[i];
    ushort4 o;
    o.x = f2bf(v.x); o.y = f2bf(v.y); o.z = f2bf(v.z); o.w = f2bf(v.w);
    dst[i] = o;
  }
}

// ---------------- per-row top-KTOK -> per-row bitmask (radix select) ---------
// v2: no keys[] LDS mirror — rows are re-read from global (L2/L3-hot after
// pass 0) with the 3-op key transform recomputed. LDS drops 53.6 KB -> 9.6 KB
// so occupancy rises 2 -> 8 blocks/CU to hide LDS-atomic serialization.
__global__ __launch_bounds__(256) void topk_rows(const float* __restrict__ x,
                                                 unsigned* __restrict__ maskT) {
  __shared__ int hist[2048];        // 8192 B
  __shared__ int wtot[4];
  __shared__ int eqpre[NC64];       // 688 B
  __shared__ int eqex[NC64];        // 688 B
  __shared__ unsigned s_band;
  __shared__ int s_kneed;

  const int t = threadIdx.x;
  const int lane = t & 63;
  const int w = t >> 6;
  const int r = blockIdx.x;
  const uint4* __restrict__ row4 = (const uint4*)(x + (size_t)r * NN);
  const unsigned* __restrict__ rowu = (const unsigned*)(x + (size_t)r * NN);

  // ---- 3-pass radix select for the KTOK-th largest key ----
  unsigned band_prefix = 0;
  int kneed = KTOK;

  for (int pass = 0; pass < 3; ++pass) {
    const int shift = (pass == 0) ? 21 : (pass == 1) ? 10 : 0;
    const int bins  = (pass == 2) ? 1024 : 2048;
    const unsigned mk = bins - 1;

    for (int i = t; i < bins; i += 256) hist[i] = 0;
    __syncthreads();

    for (int i = t; i < NN / 4; i += 256) {
      uint4 v = row4[i];
      unsigned k0 = fkey(v.x), k1 = fkey(v.y), k2 = fkey(v.z), k3 = fkey(v.w);
      if (pass == 0) {
        atomicAdd(&hist[(k0 >> shift) & mk], 1);
        atomicAdd(&hist[(k1 >> shift) & mk], 1);
        atomicAdd(&hist[(k2 >> shift) & mk], 1);
        atomicAdd(&hist[(k3 >> shift) & mk], 1);
      } else if (pass == 1) {
        if ((k0 >> 21) == band_prefix) atomicAdd(&hist[(k0 >> shift) & mk], 1);
        if ((k1 >> 21) == band_prefix) atomicAdd(&hist[(k1 >> shift) & mk], 1);
        if ((k2 >> 21) == band_prefix) atomicAdd(&hist[(k2 >> shift) & mk], 1);
        if ((k3 >> 21) == band_prefix) atomicAdd(&hist[(k3 >> shift) & mk], 1);
      } else {
        if ((k0 >> 10) == band_prefix) atomicAdd(&hist[k0 & mk], 1);
        if ((k1 >> 10) == band_prefix) atomicAdd(&hist[k1 & mk], 1);
        if ((k2 >> 10) == band_prefix) atomicAdd(&hist[k2 & mk], 1);
        if ((k3 >> 10) == band_prefix) atomicAdd(&hist[k3 & mk], 1);
      }
    }
    __syncthreads();

    // parallel suffix-select: thread t owns 8 bins [8t, 8t+8)
    const int nch = bins / 8;      // 256 (passes 0,1) or 128 (pass 2)
    const int nw  = nch >> 6;      // active waves in the scan
    int loc = 0;
    if (t < nch) {
#pragma unroll
      for (int v = 0; v < 8; ++v) loc += hist[t * 8 + v];
    }
    int incl = loc;
#pragma unroll
    for (int d = 1; d < 64; d <<= 1) {
      int o = __shfl_down(incl, d);
      if (lane + d < 64) incl += o;
    }
    if (w < nw && lane == 0) wtot[w] = incl;
    __syncthreads();
    int wsuf = 0;
    for (int u = w + 1; u < nw; ++u) wsuf += wtot[u];
    const int suf_ex = wsuf + (incl - loc);
    if (t < nch && suf_ex < kneed && suf_ex + loc >= kneed) {
      int run = suf_ex;
      for (int v = t * 8 + 7;; --v) {
        int h = hist[v];
        if (run + h >= kneed) { s_band = (unsigned)v; s_kneed = kneed - run; break; }
        run += h;
      }
    }
    __syncthreads();
    band_prefix = (pass == 0) ? s_band
                : (band_prefix << ((pass == 1) ? 11 : 10)) | s_band;
    kneed = s_kneed;
    __syncthreads();
  }

  const unsigned Tkey = band_prefix;   // exact KTOK-th largest key
  const int need = kneed;              // # equal-to-Tkey to take (lowest index first)

  // ---- per-chunk equal counts (ballot), then exclusive prefix ----
  for (int c = w; c < NC64; c += 4) {
    unsigned k = fkey(rowu[c * 64 + lane]);
    unsigned long long eb = __ballot(k == Tkey);
    if (lane == 0) eqpre[c] = __popcll(eb);
  }
  __syncthreads();
  if (t < NC64) {
    int s = 0;
    for (int c = 0; c < t; ++c) s += eqpre[c];
    eqex[t] = s;
  }
  __syncthreads();

  // ---- build mask words via ballot; stable tie-break toward lowest index ----
  for (int c = w; c < NC64; c += 4) {
    unsigned k = fkey(rowu[c * 64 + lane]);
    const bool eq = (k == Tkey);
    unsigned long long eb = __ballot(eq);
    int myrank = eqex[c] + __popcll(eb & ((1ull << lane) - 1ull));
    bool pred = (k > Tkey) || (eq && (myrank < need));
    unsigned long long pb = __ballot(pred);
    if (lane == 0) maskT[(size_t)(2 * c)     * M_DIM + r] = (unsigned)pb;
    if (lane == 1) maskT[(size_t)(2 * c + 1) * M_DIM + r] = (unsigned)(pb >> 32);
  }
}

// ---------------- bit-count votes: counts[n] = sum_r maskT bit ----------------
__global__ __launch_bounds__(256) void count_votes(const unsigned* __restrict__ maskT,
                                                   int* __restrict__ counts) {
  __shared__ int part[256 * 33];
  const int t = threadIdx.x;
  const int w = blockIdx.x;
  int c[32];
#pragma unroll
  for (int b = 0; b < 32; ++b) c[b] = 0;
  const unsigned* col = maskT + (size_t)w * M_DIM;
#pragma unroll
  for (int rep = 0; rep < M_DIM / 256; ++rep) {
    unsigned m = col[rep * 256 + t];
#pragma unroll
    for (int b = 0; b < 32; ++b) c[b] += (m >> b) & 1u;
  }
#pragma unroll
  for (int b = 0; b < 32; ++b) part[t * 33 + b] = c[b];
  __syncthreads();
  if (t < 32) {
    int s = 0;
    for (int j = 0; j < 256; ++j) s += part[j * 33 + t];
    counts[w * 32 + t] = s;
  }
}

// ---------------- stable counting sort of counts (desc value, asc index) ----------------
__global__ __launch_bounds__(256) void count_hist(const int* __restrict__ counts,
                                                  int* __restrict__ bhist,
                                                  int* __restrict__ rnk) {
  __shared__ int lc[256];
  __shared__ int lh[NBINS];
  const int b = blockIdx.x, t = threadIdx.x;
  const int n = b * 256 + t;
  const int c = counts[n];
  lc[t] = c;
  for (int i = t; i < NBINS; i += 256) lh[i] = 0;
  __syncthreads();
  atomicAdd(&lh[c], 1);
  __syncthreads();
  for (int i = t; i < NBINS; i += 256) bhist[b * NBINS + i] = lh[i];
  int rk = 0;
  for (int m = 0; m < t; ++m) rk += (lc[m] == c);
  rnk[n] = rk;
}

__global__ __launch_bounds__(256) void scan_hist(const int* __restrict__ bhist,
                                                 int* __restrict__ pre) {
  __shared__ int total[NBINS];
  __shared__ int sstart[NBINS];
  const int t = threadIdx.x;
  for (int c = t; c < NBINS; c += 256) {
    int s = 0;
    for (int h = 0; h < NCHUNK; ++h) s += bhist[h * NBINS + c];
    total[c] = s;
  }
  __syncthreads();
  if (t == 0) {
    int run = 0;
    for (int c = NBINS - 1; c >= 0; --c) { sstart[c] = run; run += total[c]; }
  }
  __syncthreads();
  for (int c = t; c < NBINS; c += 256) {
    int run = sstart[c];
    for (int h = 0; h < NCHUNK; ++h) { pre[h * NBINS + c] = run; run += bhist[h * NBINS + c]; }
  }
}

__global__ __launch_bounds__(256) void place(const int* __restrict__ counts,
                                             const int* __restrict__ rnk,
                                             const int* __restrict__ pre,
                                             int* __restrict__ sel) {
  const int b = blockIdx.x, t = threadIdx.x;
  const int n = b * 256 + t;
  const int c = counts[n];
  const int pos = pre[b * NBINS + c] + rnk[n];
  if (pos < NSEL) sel[pos] = n;
}

// ---------------- gather filtered_W ----------------
__global__ __launch_bounds__(256) void gather_w(const float* __restrict__ w,
                                                const int* __restrict__ sel,
                                                float* __restrict__ out) {
  const int j = blockIdx.x * 256 + threadIdx.x;
  const int d = blockIdx.y;
  if (j < NSEL) out[(size_t)d * NSEL + j] = w[(size_t)d * NN + sel[j]];
}

// ---------------- bf16 MFMA GEMM: C[M][N] = A[M][K] * B[N][K]^T ----------------
// v2: BK=64, double-buffered LDS (2x32KB), ONE barrier per K-step (stage
// next tile at iter top -> loads fly under ds_read+MFMA; __syncthreads'
// vmcnt(0)+lgkmcnt(0) at iter end is the only drain). Conflict-free XOR
// swizzle (granule c^=(r&7)) applied BOTH sides: pre-swizzled per-lane
// global source for global_load_lds (LDS dest stays linear, rule 21) and
// identically-swizzled ds_read offsets -> 2-way (free) bank access.
// setprio(1) around MFMA clusters (T5); bijective XCD swizzle (T1),
// 16 M-tiles per XCD chunk share one B panel.
#define BM 128
#define BN 128
#define BK 64

__device__ __forceinline__ void async16(const void* g, void* l) {
  __builtin_amdgcn_global_load_lds(
      (const __attribute__((address_space(1))) void*)g,
      (__attribute__((address_space(3))) void*)l, 16, 0, 0);
}

__global__ __launch_bounds__(256, 2) void gemm_bt(const unsigned short* __restrict__ A,
                                                  const unsigned short* __restrict__ B,
                                                  float* __restrict__ C) {
  __shared__ unsigned short sh[2][2][BM * BK];   // [buf][A/B][8192] = 64 KB

  const int t = threadIdx.x;
  const int lane = t & 63;
  const int wave = t >> 6;
  const int wm = wave >> 1, wn = wave & 1;

  // XCD-aware bijective swizzle: 512 wg, 8 XCDs -> 64 wg/XCD chunk.
  // Within a chunk order is M-major (swz&15) so one chunk walks a column
  // of 16 M-tiles sharing a single B panel (2.75 MB, L2-resident).
  const int flat = blockIdx.y * gridDim.x + blockIdx.x;   // 0..511
  const int swz = (flat & 7) * 64 + (flat >> 3);
  const int m0 = (swz & 15) * BM;
  const int n0 = (swz >> 4) * BN;

  f32x4_t acc[4][4];
#pragma unroll
  for (int i = 0; i < 4; ++i)
#pragma unroll
    for (int j = 0; j < 4; ++j) acc[i][j] = (f32x4_t){0.f, 0.f, 0.f, 0.f};

  // staging constants: granule gi = q*256+t covers [row r = gi>>3][slot gi&7];
  // the slot holds source granule c = (gi&7)^(r&7)  (inverse-swizzled source).
  size_t goff[4];
  int ldso[4];
#pragma unroll
  for (int q = 0; q < 4; ++q) {
    const int g = q * 256 + t;
    const int rr = g >> 3;
    const int cc = (g & 7) ^ (rr & 7);
    goff[q] = (size_t)rr * K_DIM + (size_t)cc * 8;   // elements
    ldso[q] = (q * 256 + (t & ~63)) * 8;             // wave-uniform base, elements
  }

  // ds_read offsets: fragment (row r, k-granule c=s*4+(lane>>4)) lives at
  // LDS granule r*8 + (c ^ (r&7)).
  int aofs[2][4], bofs[2][4];
#pragma unroll
  for (int s = 0; s < 2; ++s)
#pragma unroll
    for (int i = 0; i < 4; ++i) {
      const int rA = wm * 64 + i * 16 + (lane & 15);
      aofs[s][i] = rA * 64 + (((s * 4 + (lane >> 4)) ^ (rA & 7)) * 8);
      const int rB = wn * 64 + i * 16 + (lane & 15);
      bofs[s][i] = rB * 64 + (((s * 4 + (lane >> 4)) ^ (rB & 7)) * 8);
    }

  const unsigned short* Ab = A + (size_t)m0 * K_DIM;
  const unsigned short* Bb = B + (size_t)n0 * K_DIM;

  auto stage = [&](int buf, int kk) {
#pragma unroll
    for (int q = 0; q < 4; ++q)
      async16(Ab + goff[q] + kk, &sh[buf][0][ldso[q]]);
#pragma unroll
    for (int q = 0; q < 4; ++q)
      async16(Bb + goff[q] + kk, &sh[buf][1][ldso[q]]);
  };

  auto compute = [&](int buf) {
    const unsigned short* Ax = sh[buf][0];
    const unsigned short* Bx = sh[buf][1];
#pragma unroll
    for (int s = 0; s < 2; ++s) {
      bf16x8_t af[4], bfr[4];
#pragma unroll
      for (int i = 0; i < 4; ++i) af[i] = *(const bf16x8_t*)&Ax[aofs[s][i]];
#pragma unroll
      for (int j = 0; j < 4; ++j) bfr[j] = *(const bf16x8_t*)&Bx[bofs[s][j]];
      __builtin_amdgcn_s_setprio(1);
#pragma unroll
      for (int i = 0; i < 4; ++i)
#pragma unroll
        for (int j = 0; j < 4; ++j)
          acc[i][j] = __builtin_amdgcn_mfma_f32_16x16x32_bf16(af[i], bfr[j],
                                                              acc[i][j], 0, 0, 0);
      __builtin_amdgcn_s_setprio(0);
    }
  };

  // K pipeline: 172 tiles of BK=64. Buffer indices are compile-time
  // literals (manual 2x unroll) so alias analysis never serializes
  // stage(buf^1) against compute(buf).
  stage(0, 0);
  __syncthreads();
  int kk = BK;
  for (int p = 0; p < 85; ++p) {
    stage(1, kk); compute(0); __syncthreads(); kk += BK;
    stage(0, kk); compute(1); __syncthreads(); kk += BK;
  }
  stage(1, kk); compute(0); __syncthreads();
  compute(1);

#pragma unroll
  for (int i = 0; i < 4; ++i) {
    const int rbase = m0 + wm * 64 + i * 16 + (lane >> 4) * 4;
#pragma unroll
    for (int j = 0; j < 4; ++j) {
      const int col = n0 + wn * 64 + j * 16 + (lane & 15);
#pragma unroll
      for (int rr = 0; rr < 4; ++rr)
        C[(size_t)(rbase + rr) * N_DIM + col] = acc[i][j][rr];
    }
  }
}

// ---------------- launcher ----------------
extern "C" void kernel_launch(void* const* d_in, const int* in_sizes, int n_in,
                              void* d_out, int out_size, void* d_ws, size_t ws_size,
                              hipStream_t stream) {
  const float* x = (const float*)d_in[0];   // [1,2048,11008]
  const float* w = (const float*)d_in[1];   // [4096,11008]
  float* out = (float*)d_out;
  float* true_val = out;                                // 2048*4096
  float* filt = out + (size_t)M_DIM * N_DIM;            // 4096*4403

  char* ws = (char*)d_ws;
  unsigned short* xb = (unsigned short*)ws;                       // 45,088,768 B
  unsigned short* wb = (unsigned short*)(ws + 45088768);          // 90,177,536 B
  int* counts = (int*)(ws + 45088768 + 90177536);                 // 44,032 B
  int* rnk    = counts + NN;                                      // 44,032 B
  int* bhist  = rnk + NN;                                         // 43*2049*4 B
  int* pre    = bhist + NCHUNK * NBINS;                           // 43*2049*4 B
  int* sel    = pre + NCHUNK * NBINS;                             // 17,612 B

  // vote bitmask (344*2048 u32 = 2.8 MB) staged in the true_value output
  // region, which gemm_bt fully overwrites afterwards.
  unsigned* maskT = (unsigned*)true_val;

  cvt_f32_bf16<<<4096, 256, 0, stream>>>((const float4*)x, (ushort4*)xb, M_DIM * K_DIM / 4);
  cvt_f32_bf16<<<4096, 256, 0, stream>>>((const float4*)w, (ushort4*)wb, N_DIM * K_DIM / 4);

  topk_rows<<<M_DIM, 256, 0, stream>>>(x, maskT);
  count_votes<<<NWORDS, 256, 0, stream>>>(maskT, counts);
  count_hist<<<NCHUNK, 256, 0, stream>>>(counts, bhist, rnk);
  scan_hist<<<1, 256, 0, stream>>>(bhist, pre);
  place<<<NCHUNK, 256, 0, stream>>>(counts, rnk, pre, sel);
  gather_w<<<dim3((NSEL + 255) / 256, N_DIM), 256, 0, stream>>>(w, sel, filt);

  gemm_bt<<<dim3(N_DIM / BN, M_DIM / BM), 256, 0, stream>>>(xb, wb, true_val);
}